// Round 13
// baseline (451.866 us; speedup 1.0000x reference)
//
#include <hip/hip_runtime.h>

// ---------------------------------------------------------------------------
// VoxMLP round 19: 2-group-per-wave phase-1 pipeline (A/B, 64 pts/wave).
//   r18: request-halving neutral -> stall is dependent-load LATENCY with only
//   ~400cyc (pos-enc) of cover. Fix: issue glA+glB for two 32-pt groups up
//   front; role-1 lanes run pos-enc A THEN B (~800cyc) before role-0 consumes
//   A then B (vmcnt FIFO: wait-A = vmcnt(8), B stays in flight). One barrier,
//   then MLP-A, MLP-B (weights L1-reused twice per load). Grid 4096 blocks,
//   LDS 22.5KB/block (5 blocks = 112.6KB), (256,5) kept — phase-1 VGPR peak
//   (glA+glB+setups ~90) is disjoint from MLP peak (~100); WRITE_SIZE is the
//   spill sentinel. prep = r15 streaming (unchanged).
// ---------------------------------------------------------------------------

typedef __attribute__((ext_vector_type(4))) float f4;
typedef long long llg;                                    // 8 x fp8
typedef __attribute__((ext_vector_type(2))) long long llg2;  // 16 x fp8 (4 VGPR)
typedef unsigned long long u64;

#define MFMA8 __builtin_amdgcn_mfma_f32_16x16x32_fp8_fp8
#define SCHED_FENCE() __builtin_amdgcn_sched_barrier(0)

__device__ __forceinline__ float bf2f(unsigned int u) {
    union { float f; unsigned int i; } v; v.i = u << 16; return v.f;
}
__device__ __forceinline__ unsigned int pkbf(float a, float b) {
    unsigned int r;
    asm("v_cvt_pk_bf16_f32 %0, %1, %2" : "=v"(r) : "v"(a), "v"(b));
    return r;
}
__device__ __forceinline__ float vfract(float a) {
    float d; asm("v_fract_f32 %0, %1" : "=v"(d) : "v"(a)); return d;
}
__device__ __forceinline__ float vsin(float a) {
    float d; asm("v_sin_f32 %0, %1" : "=v"(d) : "v"(a)); return d;
}
__device__ __forceinline__ float gv(const float* __restrict__ g, int i, int j, int k) {
    return g[(i * 256 + j) * 256 + k];
}
// feature permutation: slot k' -> original feature index (or -1 = zero pad)
__device__ __forceinline__ int featmap(int kp) {
    if (kp < 3) return kp;
    if (kp == 3) return -1;
    const int m = kp - 4, b = m / 6, r = m - 6 * b, d = r >> 1, c = r & 1;
    return 3 + 6 * b + 3 * c + d;
}
// hidden-layer K permutation: storage slot k -> producing-layer unit index,
// chosen so the producer's packed C dwords are directly the B-fragment.
__device__ __forceinline__ int hidperm(int k) {
    const int kt = k >> 5, q = (k >> 3) & 3, j = k & 7;
    return 32 * kt + ((j >> 2) << 4) + (q << 2) + (j & 3);
}
__device__ __forceinline__ llg mkllg(unsigned int lo, unsigned int hi) {
    return (llg)(((unsigned long long)lo) | (((unsigned long long)hi) << 32));
}
__device__ __forceinline__ unsigned int pack8(f4 acc) {
    int d = __builtin_amdgcn_cvt_pk_fp8_f32(fmaxf(acc[0], 0.f), fmaxf(acc[1], 0.f), 0, false);
    d     = __builtin_amdgcn_cvt_pk_fp8_f32(fmaxf(acc[2], 0.f), fmaxf(acc[3], 0.f), d, true);
    return (unsigned int)d;
}

// ---- d_ws layout ----
// bytes [0, 67584): fp8 weight fragments, PAIRED layout:
//   byte = region + ((nt*KTP + ktp)*64 + lane)*16 + half*8 + j,  kt = 2*ktp+half
//   L0@0 (K64, KTP=1), L1@8192 (K128, KTP=2), L2@24576, L3@40960 (K192, KTP=3),
//   out@65536 (K128, KTP=2, NT=1, wo*2^13)
// shorts from 131072 (byte 262144): bf16x4 data grid (16.7M voxels * 8 B)
#define WS_TOTAL 67584
#define SWZ_BLOCKS 264          // 264*256 == 67584 (one byte per thread)
#define DG_BLOCKS 8192          // 2^21 threads x 8 voxels
#define DG_OFF_SH 131072
#define WS_NEED (262144ull + 16777216ull * 8ull)
#define WO_SCALE 8192.0f
#define WO_INV   (1.0f / 8192.0f)
#define INV2PI 0.15915494309189535f

__global__ __launch_bounds__(256) void prep(
    const float* __restrict__ g,
    const float* __restrict__ w0, const float* __restrict__ w1,
    const float* __restrict__ w2, const float* __restrict__ w3,
    const float* __restrict__ wo,
    unsigned char* __restrict__ ws8, unsigned short* __restrict__ dg,
    int do_dgrid)
{
    const int bid = blockIdx.x;
    if (bid < SWZ_BLOCKS) {
        // ---------------- weight swizzle -> fp8 (paired layout) -----------
        int idx = bid * 256 + threadIdx.x;
        const float* src; int base, KTP, Kact, Nact, ld;
        if (idx < 8192)       { src = w0; base = 0;     KTP = 1; Kact = 64;  Nact = 128; ld = 128; }
        else if (idx < 24576) { src = w1; base = 8192;  KTP = 2; Kact = 128; Nact = 128; ld = 128; }
        else if (idx < 40960) { src = w2; base = 24576; KTP = 2; Kact = 128; Nact = 128; ld = 128; }
        else if (idx < 65536) { src = w3; base = 40960; KTP = 3; Kact = 192; Nact = 128; ld = 128; }
        else                  { src = wo; base = 65536; KTP = 2; Kact = 128; Nact = 3;   ld = 3;   }
        int local = idx - base;
        int j    = local & 7;
        int half = (local >> 3) & 1;
        int lane = (local >> 4) & 63;
        int c    = local >> 10;
        int ktp  = c % KTP, nt = c / KTP;
        int kt   = ktp * 2 + half;
        int k = kt * 32 + ((lane >> 4) << 3) + j;   // k = kt*32 + quad*8 + j
        int n = nt * 16 + (lane & 15);              // unit = nt*16 + (lane&15)
        float v = 0.0f;
        if (k < Kact && n < Nact) {
            int ko;
            if (base == 0) {
                ko = featmap(k);                     // L0: features
            } else if (base == 40960) {
                if (k >= 128) {                      // L3 tail: features
                    int f = featmap(k - 128);
                    ko = (f < 0) ? -1 : 128 + f;
                } else {
                    ko = hidperm(k);                 // L3 head: L2 units
                }
            } else {
                ko = hidperm(k);                     // L1/L2/out: hidden units
            }
            if (ko >= 0) v = src[ko * ld + n];
            if (base == 65536) v *= WO_SCALE;        // keep wo out of fp8 underflow
        }
        int p = __builtin_amdgcn_cvt_pk_fp8_f32(v, v, 0, false);
        ws8[idx] = (unsigned char)(p & 0xff);
    } else if (do_dgrid) {
        // ---------------- data grid build (8 voxels/thread) ----------------
        const int t  = (bid - SWZ_BLOCKS) * 256 + threadIdx.x;   // [0, 2^21)
        const int k0 = (t & 31) << 3;
        const int j  = (t >> 5) & 255;
        const int i  = t >> 13;
        const float* row = g + (i * 256 + j) * 256;
        const float* rxp = g + (min(i + 1, 255) * 256 + j) * 256;
        const float* rxm = g + (max(i - 1, 0)   * 256 + j) * 256;
        const float* ryp = g + (i * 256 + min(j + 1, 255)) * 256;
        const float* rym = g + (i * 256 + max(j - 1, 0))   * 256;
        float se[8], sxp[8], sxm[8], syp[8], sym[8];
        {
            f4 a = *(const f4*)(row + k0), b = *(const f4*)(row + k0 + 4);
            #pragma unroll
            for (int q = 0; q < 4; ++q) { se[q] = a[q]; se[q + 4] = b[q]; }
            a = *(const f4*)(rxp + k0); b = *(const f4*)(rxp + k0 + 4);
            #pragma unroll
            for (int q = 0; q < 4; ++q) { sxp[q] = a[q]; sxp[q + 4] = b[q]; }
            a = *(const f4*)(rxm + k0); b = *(const f4*)(rxm + k0 + 4);
            #pragma unroll
            for (int q = 0; q < 4; ++q) { sxm[q] = a[q]; sxm[q + 4] = b[q]; }
            a = *(const f4*)(ryp + k0); b = *(const f4*)(ryp + k0 + 4);
            #pragma unroll
            for (int q = 0; q < 4; ++q) { syp[q] = a[q]; syp[q + 4] = b[q]; }
            a = *(const f4*)(rym + k0); b = *(const f4*)(rym + k0 + 4);
            #pragma unroll
            for (int q = 0; q < 4; ++q) { sym[q] = a[q]; sym[q + 4] = b[q]; }
        }
        float zv[10];
        zv[0] = row[max(k0 - 1, 0)];
        #pragma unroll
        for (int q = 0; q < 8; ++q) zv[q + 1] = se[q];
        zv[9] = row[min(k0 + 8, 255)];
        unsigned int o[16];
        #pragma unroll
        for (int q = 0; q < 8; ++q) {
            o[q * 2 + 0] = pkbf(se[q], (sxp[q] - sxm[q]) * 63.75f);
            o[q * 2 + 1] = pkbf((syp[q] - sym[q]) * 63.75f, (zv[q + 2] - zv[q]) * 63.75f);
        }
        unsigned short* dst = dg + (size_t)(((i * 256 + j) * 256 + k0)) * 4;
        #pragma unroll
        for (int q = 0; q < 4; ++q)
            *(uint4*)(dst + q * 8) = *(const uint4*)(&o[q * 4]);
    }
}

// per-wave LDS: TWO fbufs (groups A,B), each 32 rows x 88 B:
//   [0..63] fp8 features, [64..75] 3 fp32 c1..c3 stash.
#define FSTRIDE_B 88
#define WV_BYTES (32 * FSTRIDE_B)    // 2816
#define WV2 (2 * WV_BYTES)           // 5632 per wave

// trilinear setup for a point (defines suffixed locals)
#define TRI_SETUP(S, PX, PY, PZ)                                               \
    const float fx##S = ((PX) + 1.0f) * 127.5f;                                \
    const float fy##S = ((PY) + 1.0f) * 127.5f;                                \
    const float fz##S = ((PZ) + 1.0f) * 127.5f;                                \
    const float fx0##S = floorf(fx##S), fy0##S = floorf(fy##S), fz0##S = floorf(fz##S); \
    const float xd##S = fx##S - fx0##S, yd##S = fy##S - fy0##S, zd##S = fz##S - fz0##S; \
    const int ix0##S = min(max((int)fx0##S, 0), 255);                          \
    const int iy0##S = min(max((int)fy0##S, 0), 255);                          \
    const int iz0##S = min(max((int)fz0##S, 0), 255);                          \
    const int ix1##S = min(ix0##S + 1, 255);                                   \
    const int iy1##S = min(iy0##S + 1, 255);                                   \
    const int iz1##S = min(iz0##S + 1, 255);

// streamed pos-enc into FB (uses px/py/pz args)
#define POSENC(PX, PY, PZ, FB)                                                 \
    do {                                                                       \
        const float r0_ = (PX) * INV2PI, r1_ = (PY) * INV2PI, r2_ = (PZ) * INV2PI; \
        unsigned char* fb_ = (FB);                                             \
        auto slotv_ = [&](int n) -> float {                                    \
            if (n == 0) return (PX);                                           \
            if (n == 1) return (PY);                                           \
            if (n == 2) return (PZ);                                           \
            if (n == 3) return 0.0f;                                           \
            const int m_ = n - 4, b_ = m_ / 6, t_ = m_ % 6, ax_ = t_ >> 1, ph_ = t_ & 1; \
            const float rr_ = (ax_ == 0) ? r0_ : (ax_ == 1) ? r1_ : r2_;       \
            const float arg_ = rr_ * (float)(1 << b_) + (ph_ ? 0.25f : 0.0f);  \
            return vsin(vfract(arg_));                                         \
        };                                                                     \
        _Pragma("unroll")                                                      \
        for (int w_ = 0; w_ < 8; ++w_) {                                       \
            int lo_ = __builtin_amdgcn_cvt_pk_fp8_f32(slotv_(8 * w_ + 0), slotv_(8 * w_ + 1), 0, false); \
            lo_     = __builtin_amdgcn_cvt_pk_fp8_f32(slotv_(8 * w_ + 2), slotv_(8 * w_ + 3), lo_, true); \
            int hi_ = __builtin_amdgcn_cvt_pk_fp8_f32(slotv_(8 * w_ + 4), slotv_(8 * w_ + 5), 0, false); \
            hi_     = __builtin_amdgcn_cvt_pk_fp8_f32(slotv_(8 * w_ + 6), slotv_(8 * w_ + 7), hi_, true); \
            uint2 pk_; pk_.x = (unsigned int)lo_; pk_.y = (unsigned int)hi_;   \
            *(uint2*)(fb_ + w_ * 8) = pk_;                                     \
        }                                                                      \
    } while (0)

// consume 8 gathered corners (GL) with weights from setup-suffix S
#define CONSUME(S, GL, PIDX, FB)                                               \
    do {                                                                       \
        float ret0_ = 0.f, c1_ = 0.f, c2_ = 0.f, c3_ = 0.f;                    \
        _Pragma("unroll")                                                      \
        for (int c_ = 0; c_ < 8; ++c_) {                                       \
            const float wgt_ = ((c_ & 4) ? xd##S : 1.0f - xd##S) *             \
                               ((c_ & 2) ? yd##S : 1.0f - yd##S) *             \
                               ((c_ & 1) ? zd##S : 1.0f - zd##S);              \
            const unsigned int wx_ = (unsigned int)(GL)[c_];                   \
            const unsigned int wy_ = (unsigned int)((GL)[c_] >> 32);           \
            ret0_ = fmaf(wgt_, bf2f(wx_ & 0xffffu), ret0_);                    \
            c1_   = fmaf(wgt_, bf2f(wx_ >> 16),     c1_);                      \
            c2_   = fmaf(wgt_, bf2f(wy_ & 0xffffu), c2_);                      \
            c3_   = fmaf(wgt_, bf2f(wy_ >> 16),     c3_);                      \
        }                                                                      \
        out[(PIDX)] = ret0_;                                                   \
        out[B + (PIDX) * 3 + 0] = c1_;                                         \
        out[B + (PIDX) * 3 + 1] = c2_;                                         \
        out[B + (PIDX) * 3 + 2] = c3_;                                         \
        float* cst_ = (float*)((FB) + p2 * FSTRIDE_B + 64);                    \
        cst_[0] = c1_; cst_[1] = c2_; cst_[2] = c3_;                           \
    } while (0)

// Hidden layer (K=128): SRCP/DSTP are llg[2][4] pair arrays, pt-inner.
#define HIDDEN_LAYER(WSL, BIASP, SRCP, DSTP)                                    \
    do {                                                                        \
        _Pragma("unroll")                                                       \
        for (int utp = 0; utp < 4; ++utp) {                                     \
            const int utA = 2 * utp, utB = 2 * utp + 1;                         \
            llg2 wa0 = *(const llg2*)((WSL) + ((utA * 2 + 0) * 64 + lane) * 16);\
            llg2 wa1 = *(const llg2*)((WSL) + ((utA * 2 + 1) * 64 + lane) * 16);\
            llg2 wb0 = *(const llg2*)((WSL) + ((utB * 2 + 0) * 64 + lane) * 16);\
            llg2 wb1 = *(const llg2*)((WSL) + ((utB * 2 + 1) * 64 + lane) * 16);\
            const f4 biasA = *(const f4*)((BIASP) + utA * 16 + quad * 4);       \
            const f4 biasB = *(const f4*)((BIASP) + utB * 16 + quad * 4);       \
            _Pragma("unroll")                                                   \
            for (int pt = 0; pt < 2; ++pt) {                                    \
                f4 a0 = biasA, a1 = biasB;                                      \
                a0 = MFMA8(wa0[0], SRCP[pt][0], a0, 0, 0, 0);                   \
                a0 = MFMA8(wa0[1], SRCP[pt][1], a0, 0, 0, 0);                   \
                a0 = MFMA8(wa1[0], SRCP[pt][2], a0, 0, 0, 0);                   \
                a0 = MFMA8(wa1[1], SRCP[pt][3], a0, 0, 0, 0);                   \
                a1 = MFMA8(wb0[0], SRCP[pt][0], a1, 0, 0, 0);                   \
                a1 = MFMA8(wb0[1], SRCP[pt][1], a1, 0, 0, 0);                   \
                a1 = MFMA8(wb1[0], SRCP[pt][2], a1, 0, 0, 0);                   \
                a1 = MFMA8(wb1[1], SRCP[pt][3], a1, 0, 0, 0);                   \
                DSTP[pt][utp] = mkllg(pack8(a0), pack8(a1));                    \
            }                                                                   \
            SCHED_FENCE();                                                      \
        }                                                                       \
    } while (0)

// Full MLP + Rodrigues epilogue for one 32-point group.
#define MLP_BODY(FBUF, PB)                                                      \
    do {                                                                        \
        const int frow0 = lm * FSTRIDE_B + quad * 8;                            \
        llg actA[2][4];                                                         \
        llg actB[2][4];                                                         \
        llg ffp[2][2];                                                          \
        _Pragma("unroll")                                                       \
        for (int pt = 0; pt < 2; ++pt)                                          \
            _Pragma("unroll")                                                   \
            for (int kt = 0; kt < 2; ++kt)                                      \
                ffp[pt][kt] = *(const llg*)((FBUF) + pt * 16 * FSTRIDE_B + frow0 + kt * 32); \
        _Pragma("unroll")                                                       \
        for (int utp = 0; utp < 4; ++utp) {                                     \
            const int utA = 2 * utp, utB = 2 * utp + 1;                         \
            llg2 wA = *(const llg2*)(ws8 + (utA * 64 + lane) * 16);             \
            llg2 wB = *(const llg2*)(ws8 + (utB * 64 + lane) * 16);             \
            const f4 biasA = *(const f4*)(b0 + utA * 16 + quad * 4);            \
            const f4 biasB = *(const f4*)(b0 + utB * 16 + quad * 4);            \
            _Pragma("unroll")                                                   \
            for (int pt = 0; pt < 2; ++pt) {                                    \
                f4 a0 = biasA, a1 = biasB;                                      \
                a0 = MFMA8(wA[0], ffp[pt][0], a0, 0, 0, 0);                     \
                a0 = MFMA8(wA[1], ffp[pt][1], a0, 0, 0, 0);                     \
                a1 = MFMA8(wB[0], ffp[pt][0], a1, 0, 0, 0);                     \
                a1 = MFMA8(wB[1], ffp[pt][1], a1, 0, 0, 0);                     \
                actA[pt][utp] = mkllg(pack8(a0), pack8(a1));                    \
            }                                                                   \
            SCHED_FENCE();                                                      \
        }                                                                       \
        HIDDEN_LAYER(ws8 + 8192,  b1, actA, actB);                              \
        HIDDEN_LAYER(ws8 + 24576, b2, actB, actA);                              \
        _Pragma("unroll")                                                       \
        for (int utp = 0; utp < 4; ++utp) {                                     \
            const int utA = 2 * utp, utB = 2 * utp + 1;                         \
            llg2 ha0 = *(const llg2*)(ws8 + 40960 + ((utA * 3 + 0) * 64 + lane) * 16); \
            llg2 ha1 = *(const llg2*)(ws8 + 40960 + ((utA * 3 + 1) * 64 + lane) * 16); \
            llg2 ha2 = *(const llg2*)(ws8 + 40960 + ((utA * 3 + 2) * 64 + lane) * 16); \
            llg2 hb0 = *(const llg2*)(ws8 + 40960 + ((utB * 3 + 0) * 64 + lane) * 16); \
            llg2 hb1 = *(const llg2*)(ws8 + 40960 + ((utB * 3 + 1) * 64 + lane) * 16); \
            llg2 hb2 = *(const llg2*)(ws8 + 40960 + ((utB * 3 + 2) * 64 + lane) * 16); \
            const f4 biasA = *(const f4*)(b3 + utA * 16 + quad * 4);            \
            const f4 biasB = *(const f4*)(b3 + utB * 16 + quad * 4);            \
            _Pragma("unroll")                                                   \
            for (int pt = 0; pt < 2; ++pt) {                                    \
                f4 a0 = biasA, a1 = biasB;                                      \
                a0 = MFMA8(ha0[0], actA[pt][0], a0, 0, 0, 0);                   \
                a0 = MFMA8(ha0[1], actA[pt][1], a0, 0, 0, 0);                   \
                a0 = MFMA8(ha1[0], actA[pt][2], a0, 0, 0, 0);                   \
                a0 = MFMA8(ha1[1], actA[pt][3], a0, 0, 0, 0);                   \
                a0 = MFMA8(ha2[0], ffp[pt][0],  a0, 0, 0, 0);                   \
                a0 = MFMA8(ha2[1], ffp[pt][1],  a0, 0, 0, 0);                   \
                a1 = MFMA8(hb0[0], actA[pt][0], a1, 0, 0, 0);                   \
                a1 = MFMA8(hb0[1], actA[pt][1], a1, 0, 0, 0);                   \
                a1 = MFMA8(hb1[0], actA[pt][2], a1, 0, 0, 0);                   \
                a1 = MFMA8(hb1[1], actA[pt][3], a1, 0, 0, 0);                   \
                a1 = MFMA8(hb2[0], ffp[pt][0],  a1, 0, 0, 0);                   \
                a1 = MFMA8(hb2[1], ffp[pt][1],  a1, 0, 0, 0);                   \
                actB[pt][utp] = mkllg(pack8(a0), pack8(a1));                    \
            }                                                                   \
            SCHED_FENCE();                                                      \
        }                                                                       \
        const llg2 o0 = *(const llg2*)(ws8 + 65536 + (lane * 16));              \
        const llg2 o1 = *(const llg2*)(ws8 + 65536 + ((64 + lane) * 16));       \
        const float bo0 = bo[0], bo1 = bo[1], bo2 = bo[2];                      \
        _Pragma("unroll")                                                       \
        for (int pt = 0; pt < 2; ++pt) {                                        \
            f4 acc = {0.f, 0.f, 0.f, 0.f};                                      \
            acc = MFMA8(o0[0], actB[pt][0], acc, 0, 0, 0);                      \
            acc = MFMA8(o0[1], actB[pt][1], acc, 0, 0, 0);                      \
            acc = MFMA8(o1[0], actB[pt][2], acc, 0, 0, 0);                      \
            acc = MFMA8(o1[1], actB[pt][3], acc, 0, 0, 0);                      \
            const int pp = pt * 16 + lm;                                        \
            const float* cst = (const float*)((FBUF) + pp * FSTRIDE_B + 64);    \
            const float g1 = cst[0], g2 = cst[1], g3 = cst[2];                  \
            const float r0 = acc[0] * WO_INV + bo0;                             \
            const float r1 = acc[1] * WO_INV + bo1;                             \
            const float r2 = acc[2] * WO_INV + bo2;                             \
            const float theta = sqrtf(fmaf(r0, r0, fmaf(r1, r1, r2 * r2)) + 1e-12f); \
            const float it = __builtin_amdgcn_rcpf(theta);                      \
            const float e0 = r0 * it, e1 = r1 * it, e2 = r2 * it;               \
            const float a = sqrtf(fmaf(g1, g1, fmaf(g2, g2, g3 * g3)) + 1e-12f); \
            const float ia = __builtin_amdgcn_rcpf(a);                          \
            const float v0 = g1 * ia, v1 = g2 * ia, v2 = g3 * ia;               \
            const float rv = theta * INV2PI;                                    \
            const float st = vsin(vfract(rv));                                  \
            const float ct = vsin(vfract(rv + 0.25f));                          \
            const float cx = e1 * v2 - e2 * v1;                                 \
            const float cy = e2 * v0 - e0 * v2;                                 \
            const float cz = e0 * v1 - e1 * v0;                                 \
            const float om = (1.0f - ct) * (e0 * v0 + e1 * v1 + e2 * v2);       \
            if (quad == 0) {                                                    \
                const int pid2 = (PB) + pp;                                     \
                out[4 * B + pid2 * 3 + 0] = a * (ct * v0 + st * cx + om * e0);  \
                out[4 * B + pid2 * 3 + 1] = a * (ct * v1 + st * cy + om * e1);  \
                out[4 * B + pid2 * 3 + 2] = a * (ct * v2 + st * cz + om * e2);  \
            }                                                                   \
        }                                                                       \
    } while (0)

template<bool FAST>
__global__ __launch_bounds__(256, 5) void voxmlp(
    const float* __restrict__ x, const float* __restrict__ grid,
    const unsigned char* __restrict__ ws8, const unsigned short* __restrict__ dg,
    const float* __restrict__ b0, const float* __restrict__ b1,
    const float* __restrict__ b2, const float* __restrict__ b3,
    const float* __restrict__ bo,
    float* __restrict__ out, int B)
{
    __shared__ unsigned char smem[WV2 * 4];   // 22528 B

    const int lane = threadIdx.x & 63;
    const int wave = threadIdx.x >> 6;
    const int quad = lane >> 4;
    const int lm   = lane & 15;
    unsigned char* fbufA = smem + wave * WV2;
    unsigned char* fbufB = fbufA + WV_BYTES;

    const int pbase = blockIdx.x * 256 + wave * 64;   // 64 points per wave

    const int p2   = lane & 31;
    const int role = lane >> 5;
    const int pidA = pbase + p2;
    const int pidB = pbase + 32 + p2;

    const float pxA = x[pidA * 3 + 0];
    const float pyA = x[pidA * 3 + 1];
    const float pzA = x[pidA * 3 + 2];
    const float pxB = x[pidB * 3 + 0];
    const float pyB = x[pidB * 3 + 1];
    const float pzB = x[pidB * 3 + 2];

    if (FAST) {
        const unsigned char* dgb = (const unsigned char*)dg;
        TRI_SETUP(A, pxA, pyA, pzA)
        TRI_SETUP(B, pxB, pyB, pzB)
        const unsigned int vbA = (unsigned int)((ix0A * 65536 + iy0A * 256 + iz0A) << 3);
        const unsigned int oxA = (unsigned int)((ix1A - ix0A) << 19);
        const unsigned int oyA = (unsigned int)((iy1A - iy0A) << 11);
        const unsigned int ozA = (unsigned int)((iz1A - iz0A) << 3);
        const unsigned int vbB = (unsigned int)((ix0B * 65536 + iy0B * 256 + iz0B) << 3);
        const unsigned int oxB = (unsigned int)((ix1B - ix0B) << 19);
        const unsigned int oyB = (unsigned int)((iy1B - iy0B) << 11);
        const unsigned int ozB = (unsigned int)((iz1B - iz0B) << 3);

        u64 glA[8], glB[8];
        #pragma unroll
        for (int c = 0; c < 8; ++c) {
            const unsigned int off = vbA + ((c & 4) ? oxA : 0u)
                                         + ((c & 2) ? oyA : 0u)
                                         + ((c & 1) ? ozA : 0u);
            glA[c] = *(const u64*)(dgb + off);
        }
        #pragma unroll
        for (int c = 0; c < 8; ++c) {
            const unsigned int off = vbB + ((c & 4) ? oxB : 0u)
                                         + ((c & 2) ? oyB : 0u)
                                         + ((c & 1) ? ozB : 0u);
            glB[c] = *(const u64*)(dgb + off);
        }
        // pin: loads issued here, not sunk into the consume branch
        #pragma unroll
        for (int c = 0; c < 8; ++c) {
            asm volatile("" : "+v"(glA[c]));
            asm volatile("" : "+v"(glB[c]));
        }

        if (role == 1) {
            // ~800 cycles of VALU covering both gather groups
            POSENC(pxA, pyA, pzA, fbufA + p2 * FSTRIDE_B);
            POSENC(pxB, pyB, pzB, fbufB + p2 * FSTRIDE_B);
        } else {
            CONSUME(A, glA, pidA, fbufA);
            CONSUME(B, glB, pidB, fbufB);
        }
    } else {
        if (role == 0) {
            TRI_SETUP(A, pxA, pyA, pzA)
            {
                float ret0 = 0.f, c1 = 0.f, c2 = 0.f, c3 = 0.f;
                #pragma unroll
                for (int c = 0; c < 8; ++c) {
                    const int i = (c & 4) ? ix1A : ix0A;
                    const int j = (c & 2) ? iy1A : iy0A;
                    const int k = (c & 1) ? iz1A : iz0A;
                    const float wgt = ((c & 4) ? xdA : 1.0f - xdA) *
                                      ((c & 2) ? ydA : 1.0f - ydA) *
                                      ((c & 1) ? zdA : 1.0f - zdA);
                    const float v  = gv(grid, i, j, k);
                    const float gx = (gv(grid, min(i + 1, 255), j, k) - gv(grid, max(i - 1, 0), j, k)) * 63.75f;
                    const float gy = (gv(grid, i, min(j + 1, 255), k) - gv(grid, i, max(j - 1, 0), k)) * 63.75f;
                    const float gz = (gv(grid, i, j, min(k + 1, 255)) - gv(grid, i, j, max(k - 1, 0))) * 63.75f;
                    ret0 = fmaf(wgt, v,  ret0);
                    c1   = fmaf(wgt, gx, c1);
                    c2   = fmaf(wgt, gy, c2);
                    c3   = fmaf(wgt, gz, c3);
                }
                out[pidA] = ret0;
                out[B + pidA * 3 + 0] = c1;
                out[B + pidA * 3 + 1] = c2;
                out[B + pidA * 3 + 2] = c3;
                float* cst = (float*)(fbufA + p2 * FSTRIDE_B + 64);
                cst[0] = c1; cst[1] = c2; cst[2] = c3;
            }
            TRI_SETUP(B, pxB, pyB, pzB)
            {
                float ret0 = 0.f, c1 = 0.f, c2 = 0.f, c3 = 0.f;
                #pragma unroll
                for (int c = 0; c < 8; ++c) {
                    const int i = (c & 4) ? ix1B : ix0B;
                    const int j = (c & 2) ? iy1B : iy0B;
                    const int k = (c & 1) ? iz1B : iz0B;
                    const float wgt = ((c & 4) ? xdB : 1.0f - xdB) *
                                      ((c & 2) ? ydB : 1.0f - ydB) *
                                      ((c & 1) ? zdB : 1.0f - zdB);
                    const float v  = gv(grid, i, j, k);
                    const float gx = (gv(grid, min(i + 1, 255), j, k) - gv(grid, max(i - 1, 0), j, k)) * 63.75f;
                    const float gy = (gv(grid, i, min(j + 1, 255), k) - gv(grid, i, max(j - 1, 0), k)) * 63.75f;
                    const float gz = (gv(grid, i, j, min(k + 1, 255)) - gv(grid, i, j, max(k - 1, 0))) * 63.75f;
                    ret0 = fmaf(wgt, v,  ret0);
                    c1   = fmaf(wgt, gx, c1);
                    c2   = fmaf(wgt, gy, c2);
                    c3   = fmaf(wgt, gz, c3);
                }
                out[pidB] = ret0;
                out[B + pidB * 3 + 0] = c1;
                out[B + pidB * 3 + 1] = c2;
                out[B + pidB * 3 + 2] = c3;
                float* cst = (float*)(fbufB + p2 * FSTRIDE_B + 64);
                cst[0] = c1; cst[1] = c2; cst[2] = c3;
            }
        } else {
            POSENC(pxA, pyA, pzA, fbufA + p2 * FSTRIDE_B);
            POSENC(pxB, pyB, pzB, fbufB + p2 * FSTRIDE_B);
        }
    }
    __builtin_amdgcn_s_barrier();   // phase-align waves (weight L1 reuse)

    MLP_BODY(fbufA, pbase);
    MLP_BODY(fbufB, pbase + 32);
}

extern "C" void kernel_launch(void* const* d_in, const int* in_sizes, int n_in,
                              void* d_out, int out_size, void* d_ws, size_t ws_size,
                              hipStream_t stream)
{
    const float* x    = (const float*)d_in[0];
    const float* grid = (const float*)d_in[1];
    const float* w0   = (const float*)d_in[2];
    const float* b0   = (const float*)d_in[3];
    const float* w1   = (const float*)d_in[4];
    const float* b1   = (const float*)d_in[5];
    const float* w2   = (const float*)d_in[6];
    const float* b2   = (const float*)d_in[7];
    const float* w3   = (const float*)d_in[8];
    const float* b3   = (const float*)d_in[9];
    const float* wo   = (const float*)d_in[10];
    const float* bo   = (const float*)d_in[11];
    float* out = (float*)d_out;
    unsigned char* ws8 = (unsigned char*)d_ws;
    unsigned short* dg = (unsigned short*)d_ws + DG_OFF_SH;

    const int B = in_sizes[0] / 3;        // 1,048,576
    const int fast = (ws_size >= WS_NEED) ? 1 : 0;
    const int nprep = fast ? (SWZ_BLOCKS + DG_BLOCKS) : SWZ_BLOCKS;
    prep<<<nprep, 256, 0, stream>>>(grid, w0, w1, w2, w3, wo, ws8, dg, fast);
    if (fast)
        voxmlp<true><<<B / 256, 256, 0, stream>>>(x, grid, ws8, dg, b0, b1, b2, b3, bo, out, B);
    else
        voxmlp<false><<<B / 256, 256, 0, stream>>>(x, grid, ws8, dg, b0, b1, b2, b3, bo, out, B);
}